// Round 1
// baseline (1540.854 us; speedup 1.0000x reference)
//
#include <hip/hip_runtime.h>
#include <hip/hip_bf16.h>
#include <stdint.h>

typedef unsigned short u16;

#define K_OUT 11008
#define N_IN  4096
#define B_SZ  8192
#define NGRP  64

#define BM 128
#define BN 128
#define BK 64   // bf16 elems along reduction per tile

typedef __attribute__((ext_vector_type(8))) __bf16 bf16x8;
typedef __attribute__((ext_vector_type(4))) float floatx4;

__device__ __forceinline__ u16 f2bf(float f) {
    union { float f; uint32_t u; } v; v.f = f;
    uint32_t u = v.u;
    return (u16)((u + 0x7fffu + ((u >> 16) & 1u)) >> 16);  // RNE
}

__device__ __forceinline__ void load_lds_16(const u16* g, u16* l) {
    __builtin_amdgcn_global_load_lds(
        (const __attribute__((address_space(1))) unsigned int*)g,
        (__attribute__((address_space(3))) unsigned int*)l,
        16, 0, 0);
}

// xm[b,n] = bf16(x[b,n] * mu1[n])
__global__ void prep_x_kernel(const float* __restrict__ x, const float* __restrict__ mu1,
                              u16* __restrict__ xm) {
    int i = (blockIdx.x * blockDim.x + threadIdx.x) * 4;
    float4 xv = *(const float4*)(x + i);
    int n = i & (N_IN - 1);
    float4 mv = *(const float4*)(mu1 + n);
    ushort4 o;
    o.x = f2bf(xv.x * mv.x);
    o.y = f2bf(xv.y * mv.y);
    o.z = f2bf(xv.z * mv.z);
    o.w = f2bf(xv.w * mv.w);
    *(ushort4*)(xm + i) = o;
}

// Wb[k,n] = bf16((Wq[k,n] - zeros[k,g]) * scales[k,g] * mu2[k])
__global__ void prep_w_kernel(const int* __restrict__ Wq, const float* __restrict__ zeros,
                              const float* __restrict__ scales, const float* __restrict__ mu2,
                              u16* __restrict__ Wb) {
    int i = (blockIdx.x * blockDim.x + threadIdx.x) * 4;
    int k = i >> 12;            // / N_IN
    int n = i & (N_IN - 1);
    int g = n >> 6;             // all 4 elems same group (4 | 64)
    float z = zeros[k * NGRP + g];
    float s = scales[k * NGRP + g] * mu2[k];
    int4 q = *(const int4*)(Wq + i);
    ushort4 o;
    o.x = f2bf(((float)q.x - z) * s);
    o.y = f2bf(((float)q.y - z) * s);
    o.z = f2bf(((float)q.z - z) * s);
    o.w = f2bf(((float)q.w - z) * s);
    *(ushort4*)(Wb + i) = o;
}

// C[M=8192, N=11008] = A[M,Kr] * Bt[N,Kr]^T, bf16 in / fp32 out.
// 128x128 block tile, 4 waves in 2x2, each wave 64x64 via 4x4 mfma_f32_16x16x32_bf16.
__global__ __launch_bounds__(256) void gemm_bt_kernel(const u16* __restrict__ A,
                                                      const u16* __restrict__ Bt,
                                                      float* __restrict__ C) {
    __shared__ __align__(16) u16 sA[BM * BK];   // 16 KB, [row][k], k-chunks XOR-swizzled
    __shared__ __align__(16) u16 sB[BN * BK];   // 16 KB

    const int tid   = threadIdx.x;
    const int w     = tid >> 6;
    const int lane  = tid & 63;
    const int lquad = lane >> 4;
    const int l16   = lane & 15;
    const int wr    = w >> 1;
    const int wc    = w & 1;

    const int rowA = blockIdx.y * BM;   // batch-row base
    const int colB = blockIdx.x * BN;   // k-out base

    // staging: thread t fills physical 16B chunk (t&7) of row (issue*32 + t>>3).
    // physical chunk p of row r holds LOGICAL chunk p ^ (r&7)  (bank-conflict swizzle)
    const int sr  = tid >> 3;                       // row sub-index 0..31
    const int skk = ((tid & 7) ^ (sr & 7)) * 8;     // swizzled global k-offset (elems)

    floatx4 acc[4][4];
    #pragma unroll
    for (int i = 0; i < 4; ++i)
        #pragma unroll
        for (int j = 0; j < 4; ++j)
            acc[i][j] = {0.f, 0.f, 0.f, 0.f};

    for (int kb = 0; kb < N_IN; kb += BK) {
        #pragma unroll
        for (int i = 0; i < 4; ++i) {
            int r = i * 32 + sr;
            load_lds_16(A + (size_t)(rowA + r) * N_IN + kb + skk, &sA[i * 2048 + w * 512]);
        }
        #pragma unroll
        for (int i = 0; i < 4; ++i) {
            int r = i * 32 + sr;
            load_lds_16(Bt + (size_t)(colB + r) * N_IN + kb + skk, &sB[i * 2048 + w * 512]);
        }
        __syncthreads();

        #pragma unroll
        for (int ks = 0; ks < 2; ++ks) {
            bf16x8 af[4], bfr[4];
            #pragma unroll
            for (int mi = 0; mi < 4; ++mi) {
                int row = wr * 64 + mi * 16 + l16;           // A row (m), lane&15
                int lc  = ks * 4 + lquad;                    // logical chunk
                int pc  = lc ^ (row & 7);                    // physical chunk
                af[mi] = *(const bf16x8*)&sA[row * BK + pc * 8];
            }
            #pragma unroll
            for (int ni = 0; ni < 4; ++ni) {
                int row = wc * 64 + ni * 16 + l16;           // B col (n), lane&15
                int lc  = ks * 4 + lquad;
                int pc  = lc ^ (row & 7);
                bfr[ni] = *(const bf16x8*)&sB[row * BK + pc * 8];
            }
            #pragma unroll
            for (int mi = 0; mi < 4; ++mi)
                #pragma unroll
                for (int ni = 0; ni < 4; ++ni)
                    acc[mi][ni] = __builtin_amdgcn_mfma_f32_16x16x32_bf16(
                        af[mi], bfr[ni], acc[mi][ni], 0, 0, 0);
        }
        __syncthreads();
    }

    // epilogue: D col = lane&15, row = lquad*4 + reg  [m89-verified layout]
    #pragma unroll
    for (int mi = 0; mi < 4; ++mi) {
        #pragma unroll
        for (int ni = 0; ni < 4; ++ni) {
            floatx4 v = acc[mi][ni];
            int gc  = colB + wc * 64 + ni * 16 + l16;
            int gr0 = rowA + wr * 64 + mi * 16 + lquad * 4;
            #pragma unroll
            for (int r = 0; r < 4; ++r)
                C[(size_t)(gr0 + r) * K_OUT + gc] = v[r];
        }
    }
}

extern "C" void kernel_launch(void* const* d_in, const int* in_sizes, int n_in,
                              void* d_out, int out_size, void* d_ws, size_t ws_size,
                              hipStream_t stream) {
    const float* x      = (const float*)d_in[0];
    const int*   Wq     = (const int*)  d_in[1];
    const float* zeros  = (const float*)d_in[2];
    const float* scales = (const float*)d_in[3];
    const float* mu1    = (const float*)d_in[4];
    const float* mu2    = (const float*)d_in[5];
    float* out = (float*)d_out;

    u16* xm = (u16*)d_ws;                                        // 67,108,864 B
    u16* Wb = (u16*)((char*)d_ws + (size_t)B_SZ * N_IN * 2);     // 90,177,536 B

    hipLaunchKernelGGL(prep_x_kernel, dim3((B_SZ * N_IN) / 1024), dim3(256), 0, stream,
                       x, mu1, xm);
    hipLaunchKernelGGL(prep_w_kernel, dim3((K_OUT * N_IN) / 1024), dim3(256), 0, stream,
                       Wq, zeros, scales, mu2, Wb);
    hipLaunchKernelGGL(gemm_bt_kernel, dim3(K_OUT / BN, B_SZ / BM), dim3(256), 0, stream,
                       xm, Wb, out);
}

// Round 2
// 1488.544 us; speedup vs baseline: 1.0351x; 1.0351x over previous
//
#include <hip/hip_runtime.h>
#include <hip/hip_bf16.h>
#include <stdint.h>

typedef unsigned short u16;

#define K_OUT 11008
#define N_IN  4096
#define B_SZ  8192
#define NGRP  64

#define BM 128
#define BN 128
#define BK 64   // bf16 elems along reduction per tile

#define NXT (K_OUT / BN)   // 86 tiles along out-K
#define NYT (B_SZ / BM)    // 64 tiles along batch
#define PANEL 16           // panel width (x-tiles) for L3 locality

typedef __attribute__((ext_vector_type(8))) __bf16 bf16x8;
typedef __attribute__((ext_vector_type(8))) u16 u16x8;
typedef __attribute__((ext_vector_type(4))) float floatx4;

__device__ __forceinline__ u16 f2bf(float f) {
    union { float f; uint32_t u; } v; v.f = f;
    uint32_t u = v.u;
    return (u16)((u + 0x7fffu + ((u >> 16) & 1u)) >> 16);  // RNE
}

__device__ __forceinline__ void load_lds_16(const u16* g, u16* l) {
    __builtin_amdgcn_global_load_lds(
        (const __attribute__((address_space(1))) unsigned int*)g,
        (__attribute__((address_space(3))) unsigned int*)l,
        16, 0, 0);
}

// xm[b,n] = bf16(x[b,n] * mu1[n]) ; 8 elems/thread, 16B stores
__global__ __launch_bounds__(256) void prep_x_kernel(const float* __restrict__ x,
                                                     const float* __restrict__ mu1,
                                                     u16* __restrict__ xm) {
    int i = (blockIdx.x * blockDim.x + threadIdx.x) * 8;
    float4 xv0 = *(const float4*)(x + i);
    float4 xv1 = *(const float4*)(x + i + 4);
    int n = i & (N_IN - 1);
    float4 mv0 = *(const float4*)(mu1 + n);
    float4 mv1 = *(const float4*)(mu1 + n + 4);
    u16x8 o;
    o[0] = f2bf(xv0.x * mv0.x); o[1] = f2bf(xv0.y * mv0.y);
    o[2] = f2bf(xv0.z * mv0.z); o[3] = f2bf(xv0.w * mv0.w);
    o[4] = f2bf(xv1.x * mv1.x); o[5] = f2bf(xv1.y * mv1.y);
    o[6] = f2bf(xv1.z * mv1.z); o[7] = f2bf(xv1.w * mv1.w);
    *(u16x8*)(xm + i) = o;
}

// Wb[k,n] = bf16((Wq[k,n] - zeros[k,g]) * scales[k,g] * mu2[k]) ; 8 elems/thread
__global__ __launch_bounds__(256) void prep_w_kernel(const int* __restrict__ Wq,
                                                     const float* __restrict__ zeros,
                                                     const float* __restrict__ scales,
                                                     const float* __restrict__ mu2,
                                                     u16* __restrict__ Wb) {
    int i = (blockIdx.x * blockDim.x + threadIdx.x) * 8;
    int k = i >> 12;            // / N_IN
    int n = i & (N_IN - 1);
    int g = n >> 6;             // all 8 elems same group (8 | 64)
    float z = zeros[k * NGRP + g];
    float s = scales[k * NGRP + g] * mu2[k];
    int4 q0 = *(const int4*)(Wq + i);
    int4 q1 = *(const int4*)(Wq + i + 4);
    u16x8 o;
    o[0] = f2bf(((float)q0.x - z) * s); o[1] = f2bf(((float)q0.y - z) * s);
    o[2] = f2bf(((float)q0.z - z) * s); o[3] = f2bf(((float)q0.w - z) * s);
    o[4] = f2bf(((float)q1.x - z) * s); o[5] = f2bf(((float)q1.y - z) * s);
    o[6] = f2bf(((float)q1.z - z) * s); o[7] = f2bf(((float)q1.w - z) * s);
    *(u16x8*)(Wb + i) = o;
}

// C[M=8192, N=11008] = A[M,Kr] * Bt[N,Kr]^T, bf16 in / fp32 out.
// 128x128 block tile, 4 waves in 2x2, each wave 64x64 via 4x4 mfma_f32_16x16x32_bf16.
// 1D grid with panel swizzle: panels of PANEL x-tiles * all 64 y-tiles, x-fastest
// inside a panel, so ~512 concurrent blocks touch <=48 MB (L3-resident).
__global__ __launch_bounds__(256) void gemm_bt_kernel(const u16* __restrict__ A,
                                                      const u16* __restrict__ Bt,
                                                      float* __restrict__ C) {
    __shared__ __align__(16) u16 sA[BM * BK];   // 16 KB, [row][k], k-chunks XOR-swizzled
    __shared__ __align__(16) u16 sB[BN * BK];   // 16 KB

    const int tid   = threadIdx.x;
    const int w     = tid >> 6;
    const int lane  = tid & 63;
    const int lquad = lane >> 4;
    const int l16   = lane & 15;
    const int wr    = w >> 1;
    const int wc    = w & 1;

    // --- panel swizzle: bid -> (xb, yb) ---
    const int bid = blockIdx.x;
    int xb, yb;
    {
        const int per_full = PANEL * NYT;          // 1024
        const int n_full   = NXT / PANEL;          // 5 full panels (80 x-tiles)
        int p = bid / per_full;
        if (p < n_full) {
            int wi = bid - p * per_full;
            xb = p * PANEL + (wi & (PANEL - 1));
            yb = wi >> 4;                          // PANEL==16
        } else {
            int wi   = bid - n_full * per_full;
            int rem  = NXT - n_full * PANEL;       // 6
            xb = n_full * PANEL + (wi % rem);
            yb = wi / rem;
        }
    }

    const int rowA = yb * BM;   // batch-row base
    const int colB = xb * BN;   // k-out base

    // staging: thread t fills physical 16B chunk (t&7) of row (issue*32 + t>>3).
    // physical chunk p of row r holds LOGICAL chunk p ^ (r&7)  (bank-conflict swizzle)
    const int sr  = tid >> 3;                       // row sub-index 0..31
    const int skk = ((tid & 7) ^ (sr & 7)) * 8;     // swizzled global k-offset (elems)

    floatx4 acc[4][4];
    #pragma unroll
    for (int i = 0; i < 4; ++i)
        #pragma unroll
        for (int j = 0; j < 4; ++j)
            acc[i][j] = {0.f, 0.f, 0.f, 0.f};

    for (int kb = 0; kb < N_IN; kb += BK) {
        #pragma unroll
        for (int i = 0; i < 4; ++i) {
            int r = i * 32 + sr;
            load_lds_16(A + (size_t)(rowA + r) * N_IN + kb + skk, &sA[i * 2048 + w * 512]);
        }
        #pragma unroll
        for (int i = 0; i < 4; ++i) {
            int r = i * 32 + sr;
            load_lds_16(Bt + (size_t)(colB + r) * N_IN + kb + skk, &sB[i * 2048 + w * 512]);
        }
        __syncthreads();

        #pragma unroll
        for (int ks = 0; ks < 2; ++ks) {
            bf16x8 af[4], bfr[4];
            #pragma unroll
            for (int mi = 0; mi < 4; ++mi) {
                int row = wr * 64 + mi * 16 + l16;           // A row (m), lane&15
                int lc  = ks * 4 + lquad;                    // logical chunk
                int pc  = lc ^ (row & 7);                    // physical chunk
                af[mi] = *(const bf16x8*)&sA[row * BK + pc * 8];
            }
            #pragma unroll
            for (int ni = 0; ni < 4; ++ni) {
                int row = wc * 64 + ni * 16 + l16;           // B col (n), lane&15
                int lc  = ks * 4 + lquad;
                int pc  = lc ^ (row & 7);
                bfr[ni] = *(const bf16x8*)&sB[row * BK + pc * 8];
            }
            #pragma unroll
            for (int mi = 0; mi < 4; ++mi)
                #pragma unroll
                for (int ni = 0; ni < 4; ++ni)
                    acc[mi][ni] = __builtin_amdgcn_mfma_f32_16x16x32_bf16(
                        af[mi], bfr[ni], acc[mi][ni], 0, 0, 0);
        }
        __syncthreads();
    }

    // epilogue: D col = lane&15, row = lquad*4 + reg  [m89-verified layout]
    #pragma unroll
    for (int mi = 0; mi < 4; ++mi) {
        #pragma unroll
        for (int ni = 0; ni < 4; ++ni) {
            floatx4 v = acc[mi][ni];
            int gc  = colB + wc * 64 + ni * 16 + l16;
            int gr0 = rowA + wr * 64 + mi * 16 + lquad * 4;
            #pragma unroll
            for (int r = 0; r < 4; ++r)
                C[(size_t)(gr0 + r) * K_OUT + gc] = v[r];
        }
    }
}

extern "C" void kernel_launch(void* const* d_in, const int* in_sizes, int n_in,
                              void* d_out, int out_size, void* d_ws, size_t ws_size,
                              hipStream_t stream) {
    const float* x      = (const float*)d_in[0];
    const int*   Wq     = (const int*)  d_in[1];
    const float* zeros  = (const float*)d_in[2];
    const float* scales = (const float*)d_in[3];
    const float* mu1    = (const float*)d_in[4];
    const float* mu2    = (const float*)d_in[5];
    float* out = (float*)d_out;

    u16* xm = (u16*)d_ws;                                        // 67,108,864 B
    u16* Wb = (u16*)((char*)d_ws + (size_t)B_SZ * N_IN * 2);     // 90,177,536 B

    hipLaunchKernelGGL(prep_x_kernel, dim3((B_SZ * N_IN) / 2048), dim3(256), 0, stream,
                       x, mu1, xm);
    hipLaunchKernelGGL(prep_w_kernel, dim3((K_OUT * N_IN) / 2048), dim3(256), 0, stream,
                       Wq, zeros, scales, mu2, Wb);
    hipLaunchKernelGGL(gemm_bt_kernel, dim3(NXT * NYT), dim3(256), 0, stream,
                       xm, Wb, out);
}